// Round 9
// baseline (112.611 us; speedup 1.0000x reference)
//
#include <hip/hip_runtime.h>
#include <math.h>

// Problem constants (match reference)
constexpr int B_ = 32;
constexpr int C_ = 32;
constexpr int RES_ = 16;
constexpr int G_ = RES_ * RES_ * RES_;   // 4096
constexpr int N_ = 16384;
constexpr int H_ = 64;
// sqrt(3)/RES
__device__ constexpr float REG_THR = 0.10825317547305483f;

// ---------------------------------------------------------------------------
// Kernel 1: per-batch inclusive scan of counts (4096 cells) -> cum[b][G].
// ---------------------------------------------------------------------------
__global__ __launch_bounds__(256) void scan_kernel(const int* __restrict__ counts,
                                                   int* __restrict__ cum) {
    const int b = blockIdx.x;
    const int* cb = counts + b * G_;
    int* ob = cum + b * G_;

    __shared__ int partials[256];
    const int t = threadIdx.x;
    const int base = t * 16;

    int local[16];
    int s = 0;
#pragma unroll
    for (int i = 0; i < 16; ++i) {
        s += cb[base + i];
        local[i] = s;
    }
    partials[t] = s;
    __syncthreads();

    for (int off = 1; off < 256; off <<= 1) {
        int v = (t >= off) ? partials[t - off] : 0;
        __syncthreads();
        partials[t] += v;
        __syncthreads();
    }
    const int prev = (t > 0) ? partials[t - 1] : 0;

#pragma unroll
    for (int i = 0; i < 16; ++i) ob[base + i] = prev + local[i];
}

// ---------------------------------------------------------------------------
// Kernel 2 (fused Stage A+B). Block = (batch b, 64-cell tile [c0, c0+64)).
//
// Why fusion works now (each R6 failure mode individually fixed since):
//  - weights streamed via s_load serialized every wave (R4/R5, ~25-43 us)
//      -> W1/W2 staged in LDS once per block, wave-uniform broadcast reads
//         (validated in R8's hx_kernel).
//  - PADF=68 float4 LDS reads -> 842K bank conflicts (R6)
//      -> PAD=65, scalar b32 accesses; banks (cell+h)%32, conflict-free.
//  - every block re-scanned counts[0 .. c0+TC) (R6 phase 0)
//      -> separate 3 us scan kernel; each block loads only the 65 cum
//         entries covering its tile.
// Monotone idx => this tile's points are the contiguous range
// [cum[c0-1], cum[c0+63]) -> phase 2 finishes them from the LDS hx tile.
// hx never touches HBM (was 16.8+16.8 MB bf16 round-trip), fp32 accuracy
// restored, one launch gap removed, no full-G s_cum staging.
//
// LDS: s_w1 64x36 fp32 (row = W1[h][0..33], [34]=b1[h])      = 9216 B
//      s_w2 192 fp32 (+ pads)                                 =  768 B
//      s_hx 64x65 fp32                                        = 16640 B
//      s_cum 65 int                                           =  260 B
//      total ~26.9 KB -> 5 blocks/CU.
// ---------------------------------------------------------------------------
constexpr int TCELL = 64;     // cells per block
constexpr int PAD = H_ + 1;   // 65
constexpr int WROW = 36;      // W1 LDS row stride (floats)

__global__ __launch_bounds__(256) void fused_kernel(
    const float* __restrict__ x, const int* __restrict__ cum,
    const float* __restrict__ b_rnd, const float* __restrict__ W1,
    const float* __restrict__ b1, const float* __restrict__ W2,
    const float* __restrict__ b2, float* __restrict__ out0,
    float* __restrict__ reg_out) {
    const int b = blockIdx.y;
    const int c0 = blockIdx.x * TCELL;
    const int t = threadIdx.x;
    const int cell_l = t & 63;
    const int hh = __builtin_amdgcn_readfirstlane((t >> 6) * 16);

    __shared__ float s_w1[H_ * WROW];
    __shared__ float s_w2[3 * H_];
    __shared__ float s_hx[TCELL * PAD];
    __shared__ int s_cum[TCELL + 1];   // [0]=cum[c0-1], [1+i]=cum[c0+i]

    // ---- stage weights + this tile's cum slice ----
    for (int i = t; i < H_ * 34; i += 256) {
        const int r = i / 34;
        const int c = i - r * 34;
        s_w1[r * WROW + c] = W1[i];
    }
    if (t < H_) s_w1[t * WROW + 34] = b1[t];
    if (t < 3 * H_) s_w2[t] = W2[t];
    if (t < TCELL + 1) {
        const int g = c0 + t - 1;
        s_cum[t] = (g >= 0) ? cum[b * G_ + g] : 0;
    }

    // ---- x loads (issued before the barrier; HBM latency overlaps staging)
    const float* xb = x + ((size_t)b * C_) * G_ + c0 + cell_l;
    float xv[C_];
#pragma unroll
    for (int c = 0; c < C_; ++c) xv[c] = xb[(size_t)c * G_];
    __syncthreads();

    // ---- phase 1: hx tile (64 cells x 64 h) into LDS, fp32 ----
    float* row = s_hx + cell_l * PAD + hh;
#pragma unroll 4
    for (int j = 0; j < 16; ++j) {
        const float* w = s_w1 + (hh + j) * WROW;   // wave-uniform -> broadcast
        float acc = w[34];                          // b1[h]
#pragma unroll
        for (int c = 0; c < C_; ++c) acc = fmaf(w[c], xv[c], acc);
        row[j] = acc;   // banks (cell+h)%32 across lanes: conflict-free
    }
    const float b20 = b2[0], b21 = b2[1], b22 = b2[2];
    __syncthreads();

    // ---- phase 2: this tile's contiguous point range ----
    const int p_start = s_cum[0];
    const int p_end = s_cum[TCELL];

    for (int p = p_start + t; p < p_end; p += 256) {
        // smallest i in [0,64) with s_cum[1+i] > p
        int lo = 0, hi = TCELL - 1;
#pragma unroll
        for (int it = 0; it < 6; ++it) {
            const int mid = (lo + hi) >> 1;
            if (s_cum[1 + mid] > p) hi = mid; else lo = mid + 1;
        }
        const int ci = lo;
        const int idx = c0 + ci;

        const float r0 = b_rnd[((size_t)b * 2 + 0) * N_ + p];
        const float r1 = b_rnd[((size_t)b * 2 + 1) * N_ + p];
        const float* hp = s_hx + ci * PAD;

        float o0 = b20, o1 = b21, o2 = b22;
#pragma unroll 8
        for (int h = 0; h < H_; ++h) {
            float hv = hp[h];                       // ~4 lanes/cell: mix of
                                                    // broadcast + spread banks
            hv = fmaf(s_w1[h * WROW + 32], r0, hv); // uniform h -> broadcast
            hv = fmaf(s_w1[h * WROW + 33], r1, hv);
            hv = fmaxf(hv, 0.0f);
            o0 = fmaf(s_w2[h], hv, o0);
            o1 = fmaf(s_w2[H_ + h], hv, o1);
            o2 = fmaf(s_w2[2 * H_ + h], hv, o2);
        }

        const float nrm = sqrtf(o0 * o0 + o1 * o1 + o2 * o2);
        const float reg = fmaxf(nrm - REG_THR, 0.0f);

        // grid_o[k][idx] = (i_k + 0.5)/16 - 0.5, exact in fp32 from idx bits
        o0 += (float)((idx >> 8) & 15) * 0.0625f - 0.46875f;
        o1 += (float)((idx >> 4) & 15) * 0.0625f - 0.46875f;
        o2 += (float)(idx & 15) * 0.0625f - 0.46875f;

        float* op = out0 + ((size_t)b * 3) * N_ + p;
        op[0]              = o0;
        op[N_]             = o1;
        op[2 * (size_t)N_] = o2;
        reg_out[(size_t)b * N_ + p] = reg;
    }
}

// ---------------------------------------------------------------------------
extern "C" void kernel_launch(void* const* d_in, const int* in_sizes, int n_in,
                              void* d_out, int out_size, void* d_ws, size_t ws_size,
                              hipStream_t stream) {
    const float* x      = (const float*)d_in[0];  // (B, C, RES, RES, RES)
    const int*   counts = (const int*)  d_in[1];  // (B, G)
    const float* b_rnd  = (const float*)d_in[2];  // (B, 2, N)
    // d_in[3] = grid_o: unused (recomputed exactly from idx bits)
    const float* W1     = (const float*)d_in[4];  // (H, C+2)
    const float* b1     = (const float*)d_in[5];  // (H,)
    const float* W2     = (const float*)d_in[6];  // (3, H)
    const float* b2     = (const float*)d_in[7];  // (3,)

    float* out  = (float*)d_out;                  // (B, 3, N) then (B, N)
    float* rout = out + (size_t)B_ * 3 * N_;

    int* cum = (int*)d_ws;                        // B*G ints = 512 KB

    scan_kernel<<<B_, 256, 0, stream>>>(counts, cum);

    dim3 grid(G_ / TCELL, B_);
    fused_kernel<<<grid, 256, 0, stream>>>(x, cum, b_rnd, W1, b1, W2, b2,
                                           out, rout);
}

// Round 10
// 109.622 us; speedup vs baseline: 1.0273x; 1.0273x over previous
//
#include <hip/hip_runtime.h>
#include <math.h>

// Problem constants (match reference)
constexpr int B_ = 32;
constexpr int C_ = 32;
constexpr int RES_ = 16;
constexpr int G_ = RES_ * RES_ * RES_;   // 4096
constexpr int N_ = 16384;
constexpr int H_ = 64;
// sqrt(3)/RES
__device__ constexpr float REG_THR = 0.10825317547305483f;

// float -> bf16 bits, round-to-nearest-even (values are finite here).
__device__ __forceinline__ unsigned short f2bf(float f) {
    union { float f; unsigned int u; } v; v.f = f;
    const unsigned int r = v.u + 0x7FFFu + ((v.u >> 16) & 1u);
    return (unsigned short)(r >> 16);
}

// ---------------------------------------------------------------------------
// Kernel 1: per-batch inclusive scan of counts (4096 cells) -> cum[b][G].
// ---------------------------------------------------------------------------
__global__ __launch_bounds__(256) void scan_kernel(const int* __restrict__ counts,
                                                   int* __restrict__ cum) {
    const int b = blockIdx.x;
    const int* cb = counts + b * G_;
    int* ob = cum + b * G_;

    __shared__ int partials[256];
    const int t = threadIdx.x;
    const int base = t * 16;

    int local[16];
    int s = 0;
#pragma unroll
    for (int i = 0; i < 16; ++i) {
        s += cb[base + i];
        local[i] = s;
    }
    partials[t] = s;
    __syncthreads();

    for (int off = 1; off < 256; off <<= 1) {
        int v = (t >= off) ? partials[t - off] : 0;
        __syncthreads();
        partials[t] += v;
        __syncthreads();
    }
    const int prev = (t > 0) ? partials[t - 1] : 0;

#pragma unroll
    for (int i = 0; i < 16; ++i) ob[base + i] = prev + local[i];
}

// ---------------------------------------------------------------------------
// Kernel 2 (Stage A): hx_bf[b, cell, h] = bf16( b1[h] + sum_c W1[h,c]*x[..] )
//
// Best-measured configuration (R8, 110.1 us total). Design decisions, each
// counter-verified in earlier rounds:
//  - LDS copy-out, linear coalesced stores: fixes 5.8x HBM write-amp (R3).
//  - readfirstlane wave-uniform h-offset: weights never become per-lane
//    VMEM loads (R4: divergent weight addrs cost 43 us).
//  - W1/b1 staged in LDS, wave-uniform broadcast reads: removes the s_load
//    lgkmcnt serialization (R5/R7: ~25 us at VALUBusy 21% regardless of
//    wave depth).
//  - bf16 hx storage (RNE): halves the round-trip; out err ~2e-4 << 1.5e-2.
//  - 64 cells/block, PAD=65: all LDS b32 phases conflict-free; 26 KB LDS.
// ---------------------------------------------------------------------------
constexpr int TCELL = 64;     // cells per block
constexpr int PAD = H_ + 1;   // 65
constexpr int WROW = 36;      // W1 LDS row stride (floats)

__global__ __launch_bounds__(256) void hx_kernel(const float* __restrict__ x,
                                                 const float* __restrict__ W1,
                                                 const float* __restrict__ b1,
                                                 unsigned short* __restrict__ hxb) {
    const int b = blockIdx.y;
    const int tile = blockIdx.x * TCELL;
    const int t = threadIdx.x;
    const int cell_l = t & 63;                 // lane = cell
    const int hh = __builtin_amdgcn_readfirstlane((t >> 6) * 16);

    __shared__ float __align__(16) s_w1[H_ * WROW];
    __shared__ float s_hx[TCELL * PAD];

    // Cooperative W1 fill (2176 floats) + b1 into the row pad.
    for (int i = t; i < H_ * 34; i += 256) {
        const int r = i / 34;
        const int c = i - r * 34;
        s_w1[r * WROW + c] = W1[i];
    }
    if (t < H_) s_w1[t * WROW + 34] = b1[t];

    // Coalesced x loads (issue before the barrier to overlap HBM latency).
    const float* xb = x + ((size_t)b * C_) * G_ + tile + cell_l;
    float xv[C_];
#pragma unroll
    for (int c = 0; c < C_; ++c) xv[c] = xb[(size_t)c * G_];
    __syncthreads();

    // 16 h per thread; weight rows from LDS at wave-uniform addresses.
    float* row = s_hx + cell_l * PAD + hh;
#pragma unroll 4
    for (int j = 0; j < 16; ++j) {
        const float* w = s_w1 + (hh + j) * WROW;
        float acc = w[34];                     // b1[h]
#pragma unroll
        for (int c = 0; c < C_; ++c) acc = fmaf(w[c], xv[c], acc);
        row[j] = acc;   // bank = (cell + h)%32 across lanes: conflict-free
    }
    __syncthreads();

    // Copy-out: convert to bf16, pack, linear coalesced uint4 stores.
    unsigned short* ob = hxb + ((size_t)b * G_ + tile) * H_;
#pragma unroll
    for (int k = 0; k < 2; ++k) {
        const int L = (t + k * 256) * 8;       // linear element index
        const int cell = L >> 6;
        const int h = L & 63;
        const float* s = s_hx + cell * PAD + h;
        unsigned int us[4];
#pragma unroll
        for (int q = 0; q < 4; ++q) {
            const unsigned int lo = f2bf(s[2 * q]);
            const unsigned int hi = f2bf(s[2 * q + 1]);
            us[q] = lo | (hi << 16);
        }
        *(uint4*)(ob + L) = make_uint4(us[0], us[1], us[2], us[3]);
    }
}

// ---------------------------------------------------------------------------
// Kernel 3 (Stage B): one thread per (b, n) point.
//   idx = searchsorted(cum[b], n, 'right')  (binary search, LDS copy)
//   h   = relu(bf16->f32(hx[b,idx,:]) + W1[:,32]*r0 + W1[:,33]*r1)
//   out = W2 @ h + b2;  out += exact grid offset;  reg = clip(|out|-thr, 0)
// ---------------------------------------------------------------------------
__global__ __launch_bounds__(256) void point_kernel(
    const unsigned short* __restrict__ hxb, const float* __restrict__ b_rnd,
    const float* __restrict__ W1, const float* __restrict__ W2,
    const float* __restrict__ b2, const int* __restrict__ cum,
    float* __restrict__ out0, float* __restrict__ reg_out) {
    const int b = blockIdx.y;
    const int n = blockIdx.x * 256 + threadIdx.x;
    const int t = threadIdx.x;

    __shared__ int s_cum[G_];
    const int* cb = cum + b * G_;
#pragma unroll
    for (int i = 0; i < G_ / 256; ++i) s_cum[t + i * 256] = cb[t + i * 256];
    __syncthreads();

    int lo = 0, hi = G_ - 1;
#pragma unroll
    for (int it = 0; it < 12; ++it) {
        const int mid = (lo + hi) >> 1;
        if (s_cum[mid] > n) hi = mid; else lo = mid + 1;
        if (lo >= hi) hi = lo;
    }
    const int idx = lo;

    const float r0 = b_rnd[((size_t)b * 2 + 0) * N_ + n];
    const float r1 = b_rnd[((size_t)b * 2 + 1) * N_ + n];
    const unsigned short* hp = hxb + ((size_t)b * G_ + idx) * H_;

    float o0 = b2[0], o1 = b2[1], o2 = b2[2];
#pragma unroll
    for (int g = 0; g < 8; ++g) {              // 8 h per group, one uint4
        const uint4 u = *(const uint4*)(hp + g * 8);
        const unsigned int uw[4] = {u.x, u.y, u.z, u.w};
        float hvv[8];
#pragma unroll
        for (int q = 0; q < 4; ++q) {
            union { unsigned int u; float f; } a, bwd;
            a.u = uw[q] << 16;                 // even h
            bwd.u = uw[q] & 0xFFFF0000u;       // odd h
            hvv[2 * q] = a.f;
            hvv[2 * q + 1] = bwd.f;
        }
#pragma unroll
        for (int j = 0; j < 8; ++j) {
            const int h = g * 8 + j;
            float hv = hvv[j];
            hv = fmaf(W1[h * 34 + 32], r0, hv);
            hv = fmaf(W1[h * 34 + 33], r1, hv);
            hv = fmaxf(hv, 0.0f);
            o0 = fmaf(W2[0 * H_ + h], hv, o0);
            o1 = fmaf(W2[1 * H_ + h], hv, o1);
            o2 = fmaf(W2[2 * H_ + h], hv, o2);
        }
    }

    const float nrm = sqrtf(o0 * o0 + o1 * o1 + o2 * o2);
    const float reg = fmaxf(nrm - REG_THR, 0.0f);

    // grid_o[k][idx] = (i_k + 0.5)/16 - 0.5, exact in fp32 from idx bits.
    o0 += (float)((idx >> 8) & 15) * 0.0625f - 0.46875f;
    o1 += (float)((idx >> 4) & 15) * 0.0625f - 0.46875f;
    o2 += (float)(idx & 15) * 0.0625f - 0.46875f;

    float* p = out0 + ((size_t)b * 3) * N_ + n;
    p[0]              = o0;
    p[N_]             = o1;
    p[2 * (size_t)N_] = o2;
    reg_out[(size_t)b * N_ + n] = reg;
}

// ---------------------------------------------------------------------------
extern "C" void kernel_launch(void* const* d_in, const int* in_sizes, int n_in,
                              void* d_out, int out_size, void* d_ws, size_t ws_size,
                              hipStream_t stream) {
    const float* x      = (const float*)d_in[0];  // (B, C, RES, RES, RES)
    const int*   counts = (const int*)  d_in[1];  // (B, G)
    const float* b_rnd  = (const float*)d_in[2];  // (B, 2, N)
    // d_in[3] = grid_o: unused (recomputed exactly from idx bits)
    const float* W1     = (const float*)d_in[4];  // (H, C+2)
    const float* b1     = (const float*)d_in[5];  // (H,)
    const float* W2     = (const float*)d_in[6];  // (3, H)
    const float* b2     = (const float*)d_in[7];  // (3,)

    float* out  = (float*)d_out;                  // (B, 3, N) then (B, N)
    float* rout = out + (size_t)B_ * 3 * N_;

    int* cum = (int*)d_ws;                        // B*G ints = 512 KB
    unsigned short* hxb =
        (unsigned short*)((char*)d_ws + (size_t)B_ * G_ * sizeof(int));
                                                  // B*G*H bf16 = 16.8 MB

    scan_kernel<<<B_, 256, 0, stream>>>(counts, cum);

    dim3 gridA(G_ / TCELL, B_);
    hx_kernel<<<gridA, 256, 0, stream>>>(x, W1, b1, hxb);

    dim3 gridB(N_ / 256, B_);
    point_kernel<<<gridB, 256, 0, stream>>>(hxb, b_rnd, W1, W2, b2,
                                            cum, out, rout);
}